// Round 8
// baseline (570.470 us; speedup 1.0000x reference)
//
#include <hip/hip_runtime.h>
#include <float.h>

// MemN2N: B=128, M=200, S=20, Q=20, H=3 hops, V=50000, D=128
// Inputs: story int32 [B,M,S], query int32 [B,Q], E f32 [4,V,D], T f32 [4,M,D]
// Output (FP32): ahat [B,V] ++ softmax(ahat) [B,V]
// R14 vs R13 (329.3us):
//  1) revert msum nt-store (R12 without it was faster; nt un-caches msum
//     for hops' re-read).
//  2) FUSE softmax merge+normalize into the GEMM (last-block pattern):
//     blocks write {max,expsum} partials -> agent-atomic counter -> last
//     block merges to global {M,1/S} -> flag -> all blocks normalize their
//     IN-REGISTER acc and write the softmax half. Eliminates the merge
//     kernel (25.6MB re-read + launch/drain + boundary).
//     Co-residency: 36KB LDS -> 4 blk/CU (1024 slots >= 391). Cross-XCD via
//     agent-scope atomics. ctl re-zeroed each iter by hops block 0.

constexpr int Bn = 128;
constexpr int Mn = 200;
constexpr int Sn = 20;
constexpr int Qn = 20;
constexpr int Hn = 3;
constexpr int Vn = 50000;
constexpr int Dn = 128;
constexpr int CH = 100;   // fused-path chunk rows

constexpr int GTILE = 128;                       // gemm v-tile width
constexpr int NT    = (Vn + GTILE - 1) / GTILE;  // 391 tiles

constexpr int TSTR = 130;   // hops LDS panel stride (2-way bank alias = free)

constexpr size_t MSUM_ELEMS = (size_t)(Hn + 1) * Bn * Mn * Dn;  // 13,107,200
constexpr size_t SMWS_ELEMS = (size_t)NT * Bn * 2;              // partials (float2/(tile,b))
constexpr size_t SMWS_TOTAL = SMWS_ELEMS + 256 + 8;             // + gs[128]x2 + ctl

#define AT_LD(p)    __hip_atomic_load((p), __ATOMIC_RELAXED, __HIP_MEMORY_SCOPE_AGENT)
#define AT_ST(p, v) __hip_atomic_store((p), (v), __ATOMIC_RELAXED, __HIP_MEMORY_SCOPE_AGENT)

// ===========================================================================
// PATH 1: msum[t][b][m][d] = sum_s E[t][story[b][m][s]][d] + T[t][m][d]
// (R12 kernel: plain store.) float4/thread, 32 lanes/row-slot, 8 slots/block.
// ===========================================================================
__global__ __launch_bounds__(256)
void msum_kernel(const int* __restrict__ story, const float* __restrict__ E,
                 const float* __restrict__ T, float* __restrict__ msum) {
    int slot = threadIdx.x >> 5;          // 0..7
    int l    = threadIdx.x & 31;          // float4 index within row
    int row  = blockIdx.x * 8 + slot;     // t*B*M + b*M + m   (total 102,400)
    int t    = row / (Bn * Mn);
    int rem  = row - t * (Bn * Mn);
    int b    = rem / Mn;
    int m    = rem - b * Mn;

    const int* st = story + (b * Mn + m) * Sn;
    const float4* Tv = (const float4*)(T) + (size_t)(t * Mn + m) * 32;
    const float4* Et = (const float4*)(E) + (size_t)t * Vn * 32;

    int idx[Sn];
    #pragma unroll
    for (int s = 0; s < Sn; ++s) idx[s] = st[s];

    float4 acc = Tv[l];
    #pragma unroll
    for (int s = 0; s < Sn; ++s) {
        float4 e = Et[(size_t)idx[s] * 32 + l];
        acc.x += e.x; acc.y += e.y; acc.z += e.z; acc.w += e.w;
    }
    ((float4*)msum)[(size_t)row * 32 + l] = acc;
}

// ===========================================================================
// Hop chain from msum. grid = B x 1024 (16 waves), one block per b.
// R13's T14 split-stage kept. R14: block 0 zeroes the gemm ctl words.
// ===========================================================================
__global__ __launch_bounds__(1024)
void hops_kernel(const int* __restrict__ query, const float* __restrict__ E,
                 const float* __restrict__ msum, float* __restrict__ ufin,
                 unsigned int* __restrict__ ctl) {
    __shared__ __align__(16) float tileA[Mn * TSTR];   // 104,000 B
    __shared__ float u[Dn];
    __shared__ float sc[Mn];
    __shared__ float op[1024];
    __shared__ float red[16];
    __shared__ float bc[2];

    const int b    = blockIdx.x;
    const int tid  = threadIdx.x;
    const int wave = tid >> 6;
    const int lane = tid & 63;
    const int d    = tid & (Dn - 1);
    const int g    = tid >> 7;             // 0..7
    const int dq   = tid >> 8;             // 0..3 (d-quarter for scores)
    const int mm   = tid & 255;            // candidate m for scores

    if (ctl && b == 0 && tid == 0) {       // re-init fused-softmax control
        AT_ST(ctl + 0, 0u);
        AT_ST(ctl + 1, 0u);
    }

    // initial full stage of table 0
    {
        const float* src = msum + ((size_t)0 * Bn + b) * (size_t)(Mn * Dn);
        float2 vbuf[13];
        #pragma unroll
        for (int k = 0; k < 13; ++k) {
            int r = wave + 16 * k;
            if (r < Mn)
                vbuf[k] = *(const float2*)(src + (size_t)r * Dn + 2 * lane);
        }
        #pragma unroll
        for (int k = 0; k < 13; ++k) {
            int r = wave + 16 * k;
            if (r < Mn)
                *(float2*)(tileA + r * TSTR + 2 * lane) = vbuf[k];
        }
    }

    if (tid < Dn) {
        float acc = 0.f;
        const int* q = query + b * Qn;
        #pragma unroll
        for (int j = 0; j < Qn; ++j)
            acc += E[(size_t)q[j] * Dn + tid];
        u[tid] = acc;
    }
    __syncthreads();

    for (int hop = 0; hop < Hn; ++hop) {
        // T14: issue next-table global loads now (latency hides under scores)
        float2 vbuf[13];
        {
            const float* src = msum + ((size_t)(hop + 1) * Bn + b) * (size_t)(Mn * Dn);
            #pragma unroll
            for (int k = 0; k < 13; ++k) {
                int r = wave + 16 * k;
                if (r < Mn)
                    vbuf[k] = *(const float2*)(src + (size_t)r * Dn + 2 * lane);
            }
        }

        // scores from LDS
        if (mm < Mn) {
            float p = 0.f;
            #pragma unroll
            for (int i = 0; i < 32; ++i)
                p += tileA[mm * TSTR + dq * 32 + i] * u[dq * 32 + i];
            op[dq * Mn + mm] = p;
        }
        __syncthreads();   // op ready; all reads of table hop done

        // write prefetched table hop+1 (overlaps softmax)
        #pragma unroll
        for (int k = 0; k < 13; ++k) {
            int r = wave + 16 * k;
            if (r < Mn)
                *(float2*)(tileA + r * TSTR + 2 * lane) = vbuf[k];
        }

        // softmax over 200 scores
        float v = -FLT_MAX;
        if (tid < Mn)
            v = op[tid] + op[Mn + tid] + op[2 * Mn + tid] + op[3 * Mn + tid];
        float mx = v;
        #pragma unroll
        for (int off = 32; off; off >>= 1) mx = fmaxf(mx, __shfl_down(mx, off, 64));
        if (lane == 0) red[wave] = mx;
        __syncthreads();
        if (tid == 0) {
            float m0 = red[0];
            #pragma unroll
            for (int i = 1; i < 16; ++i) m0 = fmaxf(m0, red[i]);
            bc[0] = m0;
        }
        __syncthreads();
        float rmax = bc[0];
        float e = (tid < Mn) ? __expf(v - rmax) : 0.f;
        float sm = e;
        #pragma unroll
        for (int off = 32; off; off >>= 1) sm += __shfl_down(sm, off, 64);
        if (lane == 0) red[wave] = sm;
        __syncthreads();
        if (tid == 0) {
            float s = 0.f;
            #pragma unroll
            for (int i = 0; i < 16; ++i) s += red[i];
            bc[1] = s;
        }
        __syncthreads();
        float inv = 1.f / bc[1];
        if (tid < Mn) sc[tid] = e * inv;
        __syncthreads();   // sc visible; tileA writes fenced

        // o[d] = sum_m proba[m] * tileA[m][d]   (tileA = table hop+1)
        float acc = 0.f;
        #pragma unroll
        for (int k = 0; k < 25; ++k) {
            int m = g + 8 * k;
            acc += sc[m] * tileA[m * TSTR + d];
        }
        op[g * Dn + d] = acc;
        __syncthreads();
        if (tid < Dn) {
            float s = 0.f;
            #pragma unroll
            for (int i = 0; i < 8; ++i) s += op[i * Dn + tid];
            u[tid] += s;
        }
        __syncthreads();
    }
    if (tid < Dn) ufin[b * Dn + tid] = u[tid];
}

// ===========================================================================
// PATH 2 (no workspace, fallback): fused hops — unchanged.
// ===========================================================================
__global__ __launch_bounds__(1024)
void hops_fused_kernel(const int* __restrict__ story, const int* __restrict__ query,
                       const float* __restrict__ E, const float* __restrict__ T,
                       float* __restrict__ ufin) {
    __shared__ __align__(16) float tile[CH * Dn];
    __shared__ float u[Dn];
    __shared__ float sc[Mn];
    __shared__ float op[8 * Dn];
    __shared__ float red[16];
    __shared__ float bc[2];

    const int b    = blockIdx.x;
    const int tid  = threadIdx.x;
    const int wave = tid >> 6;
    const int lane = tid & 63;
    const int d    = tid & (Dn - 1);
    const int g    = tid >> 7;
    const int slot = tid >> 5;
    const int l    = tid & 31;
    const int* st  = story + b * (Mn * Sn);

    if (tid < Dn) {
        float acc = 0.f;
        const int* q = query + b * Qn;
        #pragma unroll
        for (int j = 0; j < Qn; ++j)
            acc += E[(size_t)q[j] * Dn + tid];
        u[tid] = acc;
    }

    auto build = [&](int t, int base) {
        const float4* Et = (const float4*)(E) + (size_t)t * Vn * 32;
        const float4* Tt = (const float4*)(T) + (size_t)t * Mn * 32;
        for (int m = base + slot; m < base + CH; m += 32) {
            const int* sm = st + m * Sn;
            float4 acc = Tt[(size_t)m * 32 + l];
            #pragma unroll
            for (int s = 0; s < Sn; ++s) {
                float4 e = Et[(size_t)sm[s] * 32 + l];
                acc.x += e.x; acc.y += e.y; acc.z += e.z; acc.w += e.w;
            }
            ((float4*)tile)[(m - base) * 32 + l] = acc;
        }
    };
    auto scores = [&](int base) {
        for (int m = base + wave; m < base + CH; m += 16) {
            float p = tile[(m - base) * Dn + lane]      * u[lane]
                    + tile[(m - base) * Dn + lane + 64] * u[lane + 64];
            #pragma unroll
            for (int off = 32; off; off >>= 1) p += __shfl_down(p, off, 64);
            if (lane == 0) sc[m] = p;
        }
    };

    for (int hop = 0; hop < Hn; ++hop) {
        if (hop == 0) {
            build(0, 0);  __syncthreads(); scores(0);  __syncthreads();
            build(0, CH); __syncthreads(); scores(CH); __syncthreads();
        } else {
            scores(CH); __syncthreads();
            build(hop, 0); __syncthreads(); scores(0); __syncthreads();
        }

        float v = (tid < Mn) ? sc[tid] : -FLT_MAX;
        float mx = v;
        #pragma unroll
        for (int off = 32; off; off >>= 1) mx = fmaxf(mx, __shfl_down(mx, off, 64));
        if (lane == 0) red[wave] = mx;
        __syncthreads();
        if (tid == 0) {
            float m0 = red[0];
            #pragma unroll
            for (int i = 1; i < 16; ++i) m0 = fmaxf(m0, red[i]);
            bc[0] = m0;
        }
        __syncthreads();
        float rmax = bc[0];
        float e = (tid < Mn) ? __expf(v - rmax) : 0.f;
        float sm = e;
        #pragma unroll
        for (int off = 32; off; off >>= 1) sm += __shfl_down(sm, off, 64);
        if (lane == 0) red[wave] = sm;
        __syncthreads();
        if (tid == 0) {
            float s = 0.f;
            #pragma unroll
            for (int i = 0; i < 16; ++i) s += red[i];
            bc[1] = s;
        }
        __syncthreads();
        float inv = 1.f / bc[1];
        if (tid < Mn) sc[tid] = e * inv;

        float oacc = 0.f;
        build(hop + 1, 0);
        __syncthreads();
        for (int m = g; m < CH; m += 8)
            oacc += sc[m] * tile[m * Dn + d];
        __syncthreads();
        build(hop + 1, CH);
        __syncthreads();
        for (int m = CH + g; m < 2 * CH; m += 8)
            oacc += sc[m] * tile[(m - CH) * Dn + d];
        op[g * Dn + d] = oacc;
        __syncthreads();
        if (tid < Dn) {
            float s = 0.f;
            #pragma unroll
            for (int i = 0; i < 8; ++i) s += op[i * Dn + tid];
            u[tid] += s;
        }
        __syncthreads();
    }

    if (tid < Dn) ufin[b * Dn + tid] = u[tid];
}

// ===========================================================================
// ahat GEMM + fused softmax. C[b,v] = sum_d U[b,d]*E3[v,d].
// Tile 128b x 128v (391 blocks), 256 threads (16x16), acc[8][8].
// Epilogue: partials -> counter -> last block merges {M,1/S} -> flag ->
// all blocks normalize in-register acc -> write softmax half.
// ===========================================================================
constexpr int KC   = 32;
constexpr int LSTR = 140;   // 128 cols + gaps
__device__ __forceinline__ int ldsCol(int c) { return c + 4 * (c >> 5); }

__global__ __launch_bounds__(256)
void ahat_gemm_kernel(const float* __restrict__ E, const float* __restrict__ ufin,
                      float* __restrict__ out, float* __restrict__ ws2,
                      float* __restrict__ osm) {
    __shared__ __align__(16) float uA[KC * LSTR];
    __shared__ __align__(16) float eB[KC * LSTR];
    __shared__ unsigned int amLast;
    const float* E3 = E + (size_t)Hn * Vn * Dn;

    const int tid   = threadIdx.x;
    const int tr    = tid & 15;        // b-group (8 rows each)
    const int tc    = tid >> 4;        // v-group (8 cols each)
    const int vbase = blockIdx.x * GTILE;

    const int f4 = tid & 7;            // k-float4 within chunk
    const int rr = tid >> 3;           // staging row 0..31

    float acc[8][8];
    #pragma unroll
    for (int i = 0; i < 8; ++i)
        #pragma unroll
        for (int j = 0; j < 8; ++j) acc[i][j] = 0.f;

    for (int kb = 0; kb < Dn; kb += KC) {
        #pragma unroll
        for (int i = 0; i < 4; ++i) {
            int r   = rr + 32 * i;
            int col = ldsCol(r);
            float4 uv = *(const float4*)(ufin + (size_t)r * Dn + kb + f4 * 4);
            uA[(f4 * 4 + 0) * LSTR + col] = uv.x;
            uA[(f4 * 4 + 1) * LSTR + col] = uv.y;
            uA[(f4 * 4 + 2) * LSTR + col] = uv.z;
            uA[(f4 * 4 + 3) * LSTR + col] = uv.w;
        }
        #pragma unroll
        for (int i = 0; i < 4; ++i) {
            int r  = rr + 32 * i;
            int vg = vbase + r; if (vg > Vn - 1) vg = Vn - 1;
            int col = ldsCol(r);
            float4 ev = *(const float4*)(E3 + (size_t)vg * Dn + kb + f4 * 4);
            eB[(f4 * 4 + 0) * LSTR + col] = ev.x;
            eB[(f4 * 4 + 1) * LSTR + col] = ev.y;
            eB[(f4 * 4 + 2) * LSTR + col] = ev.z;
            eB[(f4 * 4 + 3) * LSTR + col] = ev.w;
        }
        __syncthreads();
        const int ca = ldsCol(tr * 8);
        const int cb = ldsCol(tc * 8);
        #pragma unroll 2
        for (int k = 0; k < KC; ++k) {
            float4 a0 = *(const float4*)&uA[k * LSTR + ca];
            float4 a1 = *(const float4*)&uA[k * LSTR + ca + 4];
            float4 b0 = *(const float4*)&eB[k * LSTR + cb];
            float4 b1 = *(const float4*)&eB[k * LSTR + cb + 4];
            float av[8] = {a0.x, a0.y, a0.z, a0.w, a1.x, a1.y, a1.z, a1.w};
            float bv[8] = {b0.x, b0.y, b0.z, b0.w, b1.x, b1.y, b1.z, b1.w};
            #pragma unroll
            for (int i = 0; i < 8; ++i)
                #pragma unroll
                for (int j = 0; j < 8; ++j)
                    acc[i][j] += av[i] * bv[j];
        }
        __syncthreads();
    }

    const int  v0    = vbase + tc * 8;
    const bool valid = v0 < Vn;
    if (valid) {
        #pragma unroll
        for (int i = 0; i < 8; ++i) {
            int bb = tr * 8 + i;
            *(float4*)(out + (size_t)bb * Vn + v0) =
                make_float4(acc[i][0], acc[i][1], acc[i][2], acc[i][3]);
            *(float4*)(out + (size_t)bb * Vn + v0 + 4) =
                make_float4(acc[i][4], acc[i][5], acc[i][6], acc[i][7]);
        }
    }

    if (!ws2) return;   // fallback path: separate softmax kernel handles the rest

    float* gs = ws2 + SMWS_ELEMS;                 // global {M, 1/S} per row
    unsigned int* ctl = (unsigned int*)(gs + 256); // [0]=counter [1]=flag

    // ---- per-block softmax partials {max, expsum} per row ----
    #pragma unroll
    for (int i = 0; i < 8; ++i) {
        float tm = -FLT_MAX, ts = 0.f;
        if (valid) {
            #pragma unroll
            for (int j = 0; j < 8; ++j) tm = fmaxf(tm, acc[i][j]);
            #pragma unroll
            for (int j = 0; j < 8; ++j) ts += __expf(acc[i][j] - tm);
        }
        uA[tc * 128 + tr * 8 + i] = tm;
        eB[tc * 128 + tr * 8 + i] = ts;
    }
    __syncthreads();
    if (tid < Bn) {
        float M = -FLT_MAX;
        #pragma unroll
        for (int t = 0; t < 16; ++t) M = fmaxf(M, uA[t * 128 + tid]);
        float S = 0.f;
        #pragma unroll
        for (int t = 0; t < 16; ++t)
            S += eB[t * 128 + tid] * __expf(uA[t * 128 + tid] - M);
        float* wp = ws2 + ((size_t)blockIdx.x * Bn + tid) * 2;
        AT_ST(wp + 0, M);
        AT_ST(wp + 1, S);
    }
    __syncthreads();

    // ---- counter; last block merges ----
    if (tid == 0) {
        __threadfence();
        amLast = (atomicAdd(ctl + 0, 1u) == (unsigned)NT - 1) ? 1u : 0u;
    }
    __syncthreads();

    if (amLast) {
        const int r = tid & 127, h = tid >> 7;   // 2 halves of tiles per row
        float M = -FLT_MAX, S = 0.f;
        for (int i = h; i < NT; i += 8) {        // 4 tiles per pass per half
            float pm[4], ps[4]; int n = 0;
            #pragma unroll
            for (int k = 0; k < 4; ++k) {
                int t = i + 2 * k;
                if (t < NT) {
                    pm[n] = AT_LD(ws2 + ((size_t)t * Bn + r) * 2 + 0);
                    ps[n] = AT_LD(ws2 + ((size_t)t * Bn + r) * 2 + 1);
                    ++n;
                }
            }
            for (int k = 0; k < n; ++k) {
                float nm = fmaxf(M, pm[k]);
                S = S * __expf(M - nm) + ps[k] * __expf(pm[k] - nm);
                M = nm;
            }
        }
        uA[h * 128 + r] = M;
        eB[h * 128 + r] = S;
        __syncthreads();
        if (tid < 128) {
            float m0 = uA[tid], m1 = uA[128 + tid];
            float s0 = eB[tid], s1 = eB[128 + tid];
            float nm = fmaxf(m0, m1);
            float St = s0 * __expf(m0 - nm) + s1 * __expf(m1 - nm);
            AT_ST(gs + tid * 2 + 0, nm);
            AT_ST(gs + tid * 2 + 1, 1.f / St);
        }
        __syncthreads();
        if (tid == 0) {
            __threadfence();
            __hip_atomic_store(ctl + 1, 1u, __ATOMIC_RELEASE, __HIP_MEMORY_SCOPE_AGENT);
        }
    }

    // ---- spin until global {M, 1/S} ready ----
    if (tid == 0) {
        long it = 0;
        while (__hip_atomic_load(ctl + 1, __ATOMIC_ACQUIRE, __HIP_MEMORY_SCOPE_AGENT) == 0u
               && it < 100000000L) {
            ++it;
            __builtin_amdgcn_s_sleep(8);
        }
    }
    __syncthreads();

    // ---- normalize in-register acc, write softmax half ----
    if (valid) {
        #pragma unroll
        for (int i = 0; i < 8; ++i) {
            int bb = tr * 8 + i;
            float M = AT_LD(gs + bb * 2 + 0);
            float I = AT_LD(gs + bb * 2 + 1);
            *(float4*)(osm + (size_t)bb * Vn + v0) =
                make_float4(__expf(acc[i][0] - M) * I, __expf(acc[i][1] - M) * I,
                            __expf(acc[i][2] - M) * I, __expf(acc[i][3] - M) * I);
            *(float4*)(osm + (size_t)bb * Vn + v0 + 4) =
                make_float4(__expf(acc[i][4] - M) * I, __expf(acc[i][5] - M) * I,
                            __expf(acc[i][6] - M) * I, __expf(acc[i][7] - M) * I);
        }
    }
}

// ===========================================================================
// Fallback row softmax over V=50000 (fp32), 2-pass online. grid = B x 1024.
// ===========================================================================
__global__ __launch_bounds__(1024)
void softmax_kernel(const float* __restrict__ ahat, float* __restrict__ osm) {
    __shared__ float redm[16];
    __shared__ float reds[16];
    __shared__ float bc2[2];

    int b    = blockIdx.x;
    int tid  = threadIdx.x;
    int wave = tid >> 6;
    int lane = tid & 63;

    const float4* row  = (const float4*)(ahat + (size_t)b * Vn);
    float4*       orow = (float4*)(osm + (size_t)b * Vn);
    constexpr int N4 = Vn / 4;

    float m = -FLT_MAX, s = 0.f;
    for (int v = tid; v < N4; v += 1024) {
        float4 x = row[v];
        float cm = fmaxf(fmaxf(x.x, x.y), fmaxf(x.z, x.w));
        if (cm > m) { s *= __expf(m - cm); m = cm; }
        s += __expf(x.x - m) + __expf(x.y - m) + __expf(x.z - m) + __expf(x.w - m);
    }
    #pragma unroll
    for (int off = 32; off; off >>= 1) {
        float mo = __shfl_down(m, off, 64);
        float so = __shfl_down(s, off, 64);
        float nm = fmaxf(m, mo);
        s = s * __expf(m - nm) + so * __expf(mo - nm);
        m = nm;
    }
    if (lane == 0) { redm[wave] = m; reds[wave] = s; }
    __syncthreads();
    if (tid == 0) {
        float M = redm[0];
        #pragma unroll
        for (int i = 1; i < 16; ++i) M = fmaxf(M, redm[i]);
        float S = 0.f;
        #pragma unroll
        for (int i = 0; i < 16; ++i) S += reds[i] * __expf(redm[i] - M);
        bc2[0] = M; bc2[1] = 1.f / S;
    }
    __syncthreads();
    float rmax = bc2[0];
    float inv  = bc2[1];

    for (int v = tid; v < N4; v += 1024) {
        float4 x = row[v];
        orow[v] = make_float4(__expf(x.x - rmax) * inv, __expf(x.y - rmax) * inv,
                              __expf(x.z - rmax) * inv, __expf(x.w - rmax) * inv);
    }
}

// ===========================================================================
extern "C" void kernel_launch(void* const* d_in, const int* in_sizes, int n_in,
                              void* d_out, int out_size, void* d_ws, size_t ws_size,
                              hipStream_t stream) {
    const int*   story = (const int*)d_in[0];
    const int*   query = (const int*)d_in[1];
    const float* E     = (const float*)d_in[2];
    const float* T     = (const float*)d_in[3];

    float* out  = (float*)d_out;
    float* osm  = out + (size_t)Bn * Vn;
    float* ufin = osm;                      // staged in dead second output half

    const bool haveMsum = ws_size >= MSUM_ELEMS * sizeof(float);
    const bool haveSm   = ws_size >= (MSUM_ELEMS + SMWS_TOTAL) * sizeof(float);
    float* msum = (float*)d_ws;
    float* ws2  = haveSm ? ((float*)d_ws + MSUM_ELEMS) : nullptr;
    unsigned int* ctl = haveSm ? (unsigned int*)(ws2 + SMWS_ELEMS + 256) : nullptr;

    if (haveMsum) {
        msum_kernel<<<(Hn + 1) * Bn * Mn / 8, 256, 0, stream>>>(story, E, T, msum);
        hops_kernel<<<Bn, 1024, 0, stream>>>(query, E, msum, ufin, ctl);
    } else {
        hops_fused_kernel<<<Bn, 1024, 0, stream>>>(story, query, E, T, ufin);
    }

    ahat_gemm_kernel<<<NT, 256, 0, stream>>>(E, ufin, out, ws2, osm);

    if (!ws2) {
        softmax_kernel<<<Bn, 1024, 0, stream>>>(out, osm);
    }
}

// Round 9
// 324.355 us; speedup vs baseline: 1.7588x; 1.7588x over previous
//
#include <hip/hip_runtime.h>
#include <float.h>

// MemN2N: B=128, M=200, S=20, Q=20, H=3 hops, V=50000, D=128
// Inputs: story int32 [B,M,S], query int32 [B,Q], E f32 [4,V,D], T f32 [4,M,D]
// Output (FP32): ahat [B,V] ++ softmax(ahat) [B,V]
// R15: revert R14's in-kernel fused softmax (570us: cross-XCD fence/spin cost
//      ~250us — boundary drains are far cheaper than in-kernel global sync).
//      Back to R10 structure (323.1us measured). One change: gemm partials
//      LDS layout transposed to stride-17 (writes 16-way -> 4-way conflict;
//      reads 2-way). SQ_LDS_BANK_CONFLICT was 3.15M/dispatch.

constexpr int Bn = 128;
constexpr int Mn = 200;
constexpr int Sn = 20;
constexpr int Qn = 20;
constexpr int Hn = 3;
constexpr int Vn = 50000;
constexpr int Dn = 128;
constexpr int CH = 100;   // fused-path chunk rows

constexpr int GTILE = 128;                       // gemm v-tile width
constexpr int NT    = (Vn + GTILE - 1) / GTILE;  // 391 tiles
constexpr int SMCHK = 10;                        // softmax chunks per row

constexpr int TSTR = 130;   // hops LDS panel stride (2-way bank alias = free)

constexpr size_t MSUM_ELEMS = (size_t)(Hn + 1) * Bn * Mn * Dn;  // 13,107,200
constexpr size_t SMWS_ELEMS = (size_t)NT * Bn * 2;              // 100,096

// ===========================================================================
// PATH 1: msum[t][b][m][d] = sum_s E[t][story[b][m][s]][d] + T[t][m][d]
// (R6/R10 kernel, measured 136-140us.) float4/thread, 32 lanes per row-slot,
// 8 slots per 256-thread block.
// ===========================================================================
__global__ __launch_bounds__(256)
void msum_kernel(const int* __restrict__ story, const float* __restrict__ E,
                 const float* __restrict__ T, float* __restrict__ msum) {
    int slot = threadIdx.x >> 5;          // 0..7
    int l    = threadIdx.x & 31;          // float4 index within row
    int row  = blockIdx.x * 8 + slot;     // t*B*M + b*M + m   (total 102,400)
    int t    = row / (Bn * Mn);
    int rem  = row - t * (Bn * Mn);
    int b    = rem / Mn;
    int m    = rem - b * Mn;

    const int* st = story + (b * Mn + m) * Sn;
    const float4* Tv = (const float4*)(T) + (size_t)(t * Mn + m) * 32;
    const float4* Et = (const float4*)(E) + (size_t)t * Vn * 32;

    float4 acc = Tv[l];
    #pragma unroll
    for (int s = 0; s < Sn; ++s) {
        float4 e = Et[(size_t)st[s] * 32 + l];
        acc.x += e.x; acc.y += e.y; acc.z += e.z; acc.w += e.w;
    }
    ((float4*)msum)[(size_t)row * 32 + l] = acc;
}

// ===========================================================================
// Hop chain from msum. grid = B x 1024 (16 waves), one block per b.
// LDS panel tileA[200][TSTR] holds the current hop table for this b.
// (exact R10 version — measured best)
// ===========================================================================
__global__ __launch_bounds__(1024)
void hops_kernel(const int* __restrict__ query, const float* __restrict__ E,
                 const float* __restrict__ msum, float* __restrict__ ufin) {
    __shared__ __align__(16) float tileA[Mn * TSTR];   // 104,000 B
    __shared__ float u[Dn];
    __shared__ float sc[Mn];
    __shared__ float op[1024];          // reused: score partials (4x200) / o partials (8x128)
    __shared__ float red[16];
    __shared__ float bc[2];

    const int b    = blockIdx.x;
    const int tid  = threadIdx.x;
    const int wave = tid >> 6;
    const int lane = tid & 63;
    const int d    = tid & (Dn - 1);
    const int g    = tid >> 7;             // 0..7
    const int dq   = tid >> 8;             // 0..3 (d-quarter for scores)
    const int mm   = tid & 255;            // candidate m for scores

    auto stage = [&](int t) {
        const float* src = msum + ((size_t)t * Bn + b) * (size_t)(Mn * Dn);
        float2 vbuf[13];
        #pragma unroll
        for (int k = 0; k < 13; ++k) {
            int r = wave + 16 * k;
            if (r < Mn)
                vbuf[k] = *(const float2*)(src + (size_t)r * Dn + 2 * lane);
        }
        #pragma unroll
        for (int k = 0; k < 13; ++k) {
            int r = wave + 16 * k;
            if (r < Mn)
                *(float2*)(tileA + r * TSTR + 2 * lane) = vbuf[k];
        }
    };

    if (tid < Dn) {
        float acc = 0.f;
        const int* q = query + b * Qn;
        #pragma unroll
        for (int j = 0; j < Qn; ++j)
            acc += E[(size_t)q[j] * Dn + tid];
        u[tid] = acc;
    }
    stage(0);
    __syncthreads();

    for (int hop = 0; hop < Hn; ++hop) {
        // scores: thread (mm, dq) computes 32-wide partial dot from LDS
        if (mm < Mn) {
            float p = 0.f;
            #pragma unroll
            for (int i = 0; i < 32; ++i)
                p += tileA[mm * TSTR + dq * 32 + i] * u[dq * 32 + i];
            op[dq * Mn + mm] = p;
        }
        __syncthreads();

        // softmax over the 200 combined scores
        float v = -FLT_MAX;
        if (tid < Mn)
            v = op[tid] + op[Mn + tid] + op[2 * Mn + tid] + op[3 * Mn + tid];
        float mx = v;
        #pragma unroll
        for (int off = 32; off; off >>= 1) mx = fmaxf(mx, __shfl_down(mx, off, 64));
        if (lane == 0) red[wave] = mx;
        __syncthreads();
        if (tid == 0) {
            float m0 = red[0];
            #pragma unroll
            for (int i = 1; i < 16; ++i) m0 = fmaxf(m0, red[i]);
            bc[0] = m0;
        }
        __syncthreads();
        float rmax = bc[0];
        float e = (tid < Mn) ? __expf(v - rmax) : 0.f;
        float sm = e;
        #pragma unroll
        for (int off = 32; off; off >>= 1) sm += __shfl_down(sm, off, 64);
        if (lane == 0) red[wave] = sm;
        __syncthreads();
        if (tid == 0) {
            float s = 0.f;
            #pragma unroll
            for (int i = 0; i < 16; ++i) s += red[i];
            bc[1] = s;
        }
        __syncthreads();
        float inv = 1.f / bc[1];
        if (tid < Mn) sc[tid] = e * inv;

        // stage next table (C for this hop, A for the next)
        stage(hop + 1);
        __syncthreads();   // covers sc write + staging

        // o[d] = sum_m proba[m] * tileA[m][d]
        float acc = 0.f;
        #pragma unroll
        for (int k = 0; k < 25; ++k) {
            int m = g + 8 * k;
            acc += sc[m] * tileA[m * TSTR + d];
        }
        op[g * Dn + d] = acc;
        __syncthreads();
        if (tid < Dn) {
            float s = 0.f;
            #pragma unroll
            for (int i = 0; i < 8; ++i) s += op[i * Dn + tid];
            u[tid] += s;
        }
        __syncthreads();
    }
    if (tid < Dn) ufin[b * Dn + tid] = u[tid];
}

// ===========================================================================
// PATH 2 (no workspace, fallback): fused hops — unchanged.
// ===========================================================================
__global__ __launch_bounds__(1024)
void hops_fused_kernel(const int* __restrict__ story, const int* __restrict__ query,
                       const float* __restrict__ E, const float* __restrict__ T,
                       float* __restrict__ ufin) {
    __shared__ __align__(16) float tile[CH * Dn];
    __shared__ float u[Dn];
    __shared__ float sc[Mn];
    __shared__ float op[8 * Dn];
    __shared__ float red[16];
    __shared__ float bc[2];

    const int b    = blockIdx.x;
    const int tid  = threadIdx.x;
    const int wave = tid >> 6;
    const int lane = tid & 63;
    const int d    = tid & (Dn - 1);
    const int g    = tid >> 7;
    const int slot = tid >> 5;
    const int l    = tid & 31;
    const int* st  = story + b * (Mn * Sn);

    if (tid < Dn) {
        float acc = 0.f;
        const int* q = query + b * Qn;
        #pragma unroll
        for (int j = 0; j < Qn; ++j)
            acc += E[(size_t)q[j] * Dn + tid];
        u[tid] = acc;
    }

    auto build = [&](int t, int base) {
        const float4* Et = (const float4*)(E) + (size_t)t * Vn * 32;
        const float4* Tt = (const float4*)(T) + (size_t)t * Mn * 32;
        for (int m = base + slot; m < base + CH; m += 32) {
            const int* sm = st + m * Sn;
            float4 acc = Tt[(size_t)m * 32 + l];
            #pragma unroll
            for (int s = 0; s < Sn; ++s) {
                float4 e = Et[(size_t)sm[s] * 32 + l];
                acc.x += e.x; acc.y += e.y; acc.z += e.z; acc.w += e.w;
            }
            ((float4*)tile)[(m - base) * 32 + l] = acc;
        }
    };
    auto scores = [&](int base) {
        for (int m = base + wave; m < base + CH; m += 16) {
            float p = tile[(m - base) * Dn + lane]      * u[lane]
                    + tile[(m - base) * Dn + lane + 64] * u[lane + 64];
            #pragma unroll
            for (int off = 32; off; off >>= 1) p += __shfl_down(p, off, 64);
            if (lane == 0) sc[m] = p;
        }
    };

    for (int hop = 0; hop < Hn; ++hop) {
        if (hop == 0) {
            build(0, 0);  __syncthreads(); scores(0);  __syncthreads();
            build(0, CH); __syncthreads(); scores(CH); __syncthreads();
        } else {
            scores(CH); __syncthreads();
            build(hop, 0); __syncthreads(); scores(0); __syncthreads();
        }

        float v = (tid < Mn) ? sc[tid] : -FLT_MAX;
        float mx = v;
        #pragma unroll
        for (int off = 32; off; off >>= 1) mx = fmaxf(mx, __shfl_down(mx, off, 64));
        if (lane == 0) red[wave] = mx;
        __syncthreads();
        if (tid == 0) {
            float m0 = red[0];
            #pragma unroll
            for (int i = 1; i < 16; ++i) m0 = fmaxf(m0, red[i]);
            bc[0] = m0;
        }
        __syncthreads();
        float rmax = bc[0];
        float e = (tid < Mn) ? __expf(v - rmax) : 0.f;
        float sm = e;
        #pragma unroll
        for (int off = 32; off; off >>= 1) sm += __shfl_down(sm, off, 64);
        if (lane == 0) red[wave] = sm;
        __syncthreads();
        if (tid == 0) {
            float s = 0.f;
            #pragma unroll
            for (int i = 0; i < 16; ++i) s += red[i];
            bc[1] = s;
        }
        __syncthreads();
        float inv = 1.f / bc[1];
        if (tid < Mn) sc[tid] = e * inv;

        float oacc = 0.f;
        build(hop + 1, 0);
        __syncthreads();
        for (int m = g; m < CH; m += 8)
            oacc += sc[m] * tile[m * Dn + d];
        __syncthreads();
        build(hop + 1, CH);
        __syncthreads();
        for (int m = CH + g; m < 2 * CH; m += 8)
            oacc += sc[m] * tile[(m - CH) * Dn + d];
        op[g * Dn + d] = oacc;
        __syncthreads();
        if (tid < Dn) {
            float s = 0.f;
            #pragma unroll
            for (int i = 0; i < 8; ++i) s += op[i * Dn + tid];
            u[tid] += s;
        }
        __syncthreads();
    }

    if (tid < Dn) ufin[b * Dn + tid] = u[tid];
}

// ===========================================================================
// ahat GEMM: C[b,v] = sum_d U[b,d]*E3[v,d].  M=128, N=50000, K=128.
// Tile 128b x 128v (391 blocks), 256 threads (16 tr x 16 tc), acc[8][8].
// Epilogue: per-(row, vtile) softmax partials {max, expsum} -> ws2.
// R15: partials staged in LDS as [row][tile] stride-17 (was [tile*128+row]:
// 16-way write conflict). Writes now 4-way (~free), reads 2-way (free).
// ===========================================================================
constexpr int KC   = 32;
constexpr int LSTR = 140;   // 128 cols + gaps
constexpr int PSTR = 17;    // partials stride (128 rows x 16 tiles, stride 17)
__device__ __forceinline__ int ldsCol(int c) { return c + 4 * (c >> 5); }

__global__ __launch_bounds__(256)
void ahat_gemm_kernel(const float* __restrict__ E, const float* __restrict__ ufin,
                      float* __restrict__ out, float* __restrict__ ws2) {
    __shared__ __align__(16) float uA[KC * LSTR];
    __shared__ __align__(16) float eB[KC * LSTR];
    const float* E3 = E + (size_t)Hn * Vn * Dn;

    const int tid   = threadIdx.x;
    const int tr    = tid & 15;        // b-group (8 rows each)
    const int tc    = tid >> 4;        // v-group (8 cols each)
    const int vbase = blockIdx.x * GTILE;

    const int f4 = tid & 7;            // k-float4 within chunk
    const int rr = tid >> 3;           // staging row 0..31

    float acc[8][8];
    #pragma unroll
    for (int i = 0; i < 8; ++i)
        #pragma unroll
        for (int j = 0; j < 8; ++j) acc[i][j] = 0.f;

    for (int kb = 0; kb < Dn; kb += KC) {
        #pragma unroll
        for (int i = 0; i < 4; ++i) {
            int r   = rr + 32 * i;
            int col = ldsCol(r);
            float4 uv = *(const float4*)(ufin + (size_t)r * Dn + kb + f4 * 4);
            uA[(f4 * 4 + 0) * LSTR + col] = uv.x;
            uA[(f4 * 4 + 1) * LSTR + col] = uv.y;
            uA[(f4 * 4 + 2) * LSTR + col] = uv.z;
            uA[(f4 * 4 + 3) * LSTR + col] = uv.w;
        }
        #pragma unroll
        for (int i = 0; i < 4; ++i) {
            int r  = rr + 32 * i;
            int vg = vbase + r; if (vg > Vn - 1) vg = Vn - 1;
            int col = ldsCol(r);
            float4 ev = *(const float4*)(E3 + (size_t)vg * Dn + kb + f4 * 4);
            eB[(f4 * 4 + 0) * LSTR + col] = ev.x;
            eB[(f4 * 4 + 1) * LSTR + col] = ev.y;
            eB[(f4 * 4 + 2) * LSTR + col] = ev.z;
            eB[(f4 * 4 + 3) * LSTR + col] = ev.w;
        }
        __syncthreads();
        const int ca = ldsCol(tr * 8);
        const int cb = ldsCol(tc * 8);
        #pragma unroll 2
        for (int k = 0; k < KC; ++k) {
            float4 a0 = *(const float4*)&uA[k * LSTR + ca];
            float4 a1 = *(const float4*)&uA[k * LSTR + ca + 4];
            float4 b0 = *(const float4*)&eB[k * LSTR + cb];
            float4 b1 = *(const float4*)&eB[k * LSTR + cb + 4];
            float av[8] = {a0.x, a0.y, a0.z, a0.w, a1.x, a1.y, a1.z, a1.w};
            float bv[8] = {b0.x, b0.y, b0.z, b0.w, b1.x, b1.y, b1.z, b1.w};
            #pragma unroll
            for (int i = 0; i < 8; ++i)
                #pragma unroll
                for (int j = 0; j < 8; ++j)
                    acc[i][j] += av[i] * bv[j];
        }
        __syncthreads();
    }

    const int  v0    = vbase + tc * 8;   // group fully valid or fully out
    const bool valid = v0 < Vn;
    if (valid) {
        #pragma unroll
        for (int i = 0; i < 8; ++i) {
            int bb = tr * 8 + i;
            *(float4*)(out + (size_t)bb * Vn + v0) =
                make_float4(acc[i][0], acc[i][1], acc[i][2], acc[i][3]);
            *(float4*)(out + (size_t)bb * Vn + v0 + 4) =
                make_float4(acc[i][4], acc[i][5], acc[i][6], acc[i][7]);
        }
    }

    if (ws2) {
        // per-thread {max, expsum} over its 8 cols, for each of its 8 rows
        // layout: [row (tr*8+i)] x [tile tc], stride PSTR=17
        #pragma unroll
        for (int i = 0; i < 8; ++i) {
            float tm = -FLT_MAX, ts = 0.f;
            if (valid) {
                #pragma unroll
                for (int j = 0; j < 8; ++j) tm = fmaxf(tm, acc[i][j]);
                #pragma unroll
                for (int j = 0; j < 8; ++j) ts += __expf(acc[i][j] - tm);
            }
            uA[(tr * 8 + i) * PSTR + tc] = tm;
            eB[(tr * 8 + i) * PSTR + tc] = ts;
        }
        __syncthreads();
        if (tid < Bn) {
            float M = -FLT_MAX;
            #pragma unroll
            for (int t = 0; t < 16; ++t) M = fmaxf(M, uA[tid * PSTR + t]);
            float S = 0.f;
            #pragma unroll
            for (int t = 0; t < 16; ++t)
                S += eB[tid * PSTR + t] * __expf(uA[tid * PSTR + t] - M);
            float2* w = (float2*)ws2;
            w[(size_t)blockIdx.x * Bn + tid] = make_float2(M, S);
        }
    }
}

// ===========================================================================
// Softmax merge + normalize. grid = (SMCHK, B) x 256. (exact R10)
// ===========================================================================
__global__ __launch_bounds__(256)
void softmax_merge_kernel(const float* __restrict__ ahat, const float* __restrict__ ws2,
                          float* __restrict__ osm) {
    __shared__ float redm[4], reds[4];
    __shared__ float bcM, bcI;

    const int ck   = blockIdx.x;
    const int b    = blockIdx.y;
    const int tid  = threadIdx.x;
    const int wave = tid >> 6;
    const int lane = tid & 63;

    float m = -FLT_MAX, s = 0.f;
    const float2* w = (const float2*)ws2;
    for (int i = tid; i < NT; i += 256) {
        float2 p = w[(size_t)i * Bn + b];
        float nm = fmaxf(m, p.x);
        s = s * __expf(m - nm) + p.y * __expf(p.x - nm);
        m = nm;
    }
    #pragma unroll
    for (int off = 32; off; off >>= 1) {
        float mo = __shfl_down(m, off, 64);
        float so = __shfl_down(s, off, 64);
        float nm = fmaxf(m, mo);
        s = s * __expf(m - nm) + so * __expf(mo - nm);
        m = nm;
    }
    if (lane == 0) { redm[wave] = m; reds[wave] = s; }
    __syncthreads();
    if (tid == 0) {
        float M = redm[0];
        #pragma unroll
        for (int i = 1; i < 4; ++i) M = fmaxf(M, redm[i]);
        float S = 0.f;
        #pragma unroll
        for (int i = 0; i < 4; ++i) S += reds[i] * __expf(redm[i] - M);
        bcM = M; bcI = 1.f / S;
    }
    __syncthreads();
    const float M   = bcM;
    const float inv = bcI;

    constexpr int C4 = Vn / SMCHK / 4;   // 1250 float4 per chunk
    const float4* row  = (const float4*)(ahat + (size_t)b * Vn) + (size_t)ck * C4;
    float4*       orow = (float4*)(osm + (size_t)b * Vn) + (size_t)ck * C4;
    for (int v = tid; v < C4; v += 256) {
        float4 x = row[v];
        orow[v] = make_float4(__expf(x.x - M) * inv, __expf(x.y - M) * inv,
                              __expf(x.z - M) * inv, __expf(x.w - M) * inv);
    }
}

// ===========================================================================
// Fallback row softmax over V=50000 (fp32), 2-pass online. grid = B x 1024.
// ===========================================================================
__global__ __launch_bounds__(1024)
void softmax_kernel(const float* __restrict__ ahat, float* __restrict__ osm) {
    __shared__ float redm[16];
    __shared__ float reds[16];
    __shared__ float bc2[2];

    int b    = blockIdx.x;
    int tid  = threadIdx.x;
    int wave = tid >> 6;
    int lane = tid & 63;

    const float4* row  = (const float4*)(ahat + (size_t)b * Vn);
    float4*       orow = (float4*)(osm + (size_t)b * Vn);
    constexpr int N4 = Vn / 4;

    float m = -FLT_MAX, s = 0.f;
    for (int v = tid; v < N4; v += 1024) {
        float4 x = row[v];
        float cm = fmaxf(fmaxf(x.x, x.y), fmaxf(x.z, x.w));
        if (cm > m) { s *= __expf(m - cm); m = cm; }
        s += __expf(x.x - m) + __expf(x.y - m) + __expf(x.z - m) + __expf(x.w - m);
    }
    #pragma unroll
    for (int off = 32; off; off >>= 1) {
        float mo = __shfl_down(m, off, 64);
        float so = __shfl_down(s, off, 64);
        float nm = fmaxf(m, mo);
        s = s * __expf(m - nm) + so * __expf(mo - nm);
        m = nm;
    }
    if (lane == 0) { redm[wave] = m; reds[wave] = s; }
    __syncthreads();
    if (tid == 0) {
        float M = redm[0];
        #pragma unroll
        for (int i = 1; i < 16; ++i) M = fmaxf(M, redm[i]);
        float S = 0.f;
        #pragma unroll
        for (int i = 0; i < 16; ++i) S += reds[i] * __expf(redm[i] - M);
        bc2[0] = M; bc2[1] = 1.f / S;
    }
    __syncthreads();
    float rmax = bc2[0];
    float inv  = bc2[1];

    for (int v = tid; v < N4; v += 1024) {
        float4 x = row[v];
        orow[v] = make_float4(__expf(x.x - rmax) * inv, __expf(x.y - rmax) * inv,
                              __expf(x.z - rmax) * inv, __expf(x.w - rmax) * inv);
    }
}

// ===========================================================================
extern "C" void kernel_launch(void* const* d_in, const int* in_sizes, int n_in,
                              void* d_out, int out_size, void* d_ws, size_t ws_size,
                              hipStream_t stream) {
    const int*   story = (const int*)d_in[0];
    const int*   query = (const int*)d_in[1];
    const float* E     = (const float*)d_in[2];
    const float* T     = (const float*)d_in[3];

    float* out  = (float*)d_out;
    float* ufin = out + (size_t)Bn * Vn;   // staged in dead second output half

    const bool haveMsum = ws_size >= MSUM_ELEMS * sizeof(float);
    const bool haveSm   = ws_size >= (MSUM_ELEMS + SMWS_ELEMS) * sizeof(float);
    float* msum = (float*)d_ws;
    float* ws2  = haveSm ? ((float*)d_ws + MSUM_ELEMS) : nullptr;

    if (haveMsum) {
        msum_kernel<<<(Hn + 1) * Bn * Mn / 8, 256, 0, stream>>>(story, E, T, msum);
        hops_kernel<<<Bn, 1024, 0, stream>>>(query, E, msum, ufin);
    } else {
        hops_fused_kernel<<<Bn, 1024, 0, stream>>>(story, query, E, T, ufin);
    }

    ahat_gemm_kernel<<<NT, 256, 0, stream>>>(E, ufin, out, ws2);

    if (ws2) {
        softmax_merge_kernel<<<dim3(SMCHK, Bn), 256, 0, stream>>>(
            out, ws2, out + (size_t)Bn * Vn);
    } else {
        softmax_kernel<<<Bn, 1024, 0, stream>>>(out, out + (size_t)Bn * Vn);
    }
}